// Round 2
// baseline (871.824 us; speedup 1.0000x reference)
//
#include <hip/hip_runtime.h>
#include <stdint.h>

// ---------------------------------------------------------------------------
// LawinAttn fused pipeline for MI355X (gfx950).
// k0 prep (bf16 weights + BN fold), k1 posmix (-> q-major ctx2),
// k2 theta/phi/g projections (MFMA GEMM, HEAD-MAJOR output [n][h][q][d]),
// k3 per-head attention (contiguous per-head slices), k4 out proj.
// ---------------------------------------------------------------------------

typedef short bf16x8 __attribute__((ext_vector_type(8)));
typedef float f32x4 __attribute__((ext_vector_type(4)));

#define MFMA16(a, b, c) __builtin_amdgcn_mfma_f32_16x16x32_bf16((a), (b), (c), 0, 0, 0)

// ws byte offsets
#define WS_W     0u           // 4 x 131072 bf16 weights: [theta|phi|g|out]
#define WS_BN    1048576u     // 2560 f32
#define WS_PMW   1058816u     // 262144 bf16 (pm_W)
#define WS_CTX2  2097152u     // 1024*64*512 bf16 q-major ctx2 (later reused as y)
#define WS_THQ   69206016u    // 3 x 1024*64*256 bf16 HEAD-MAJOR theta/phi/g
#define WS_YHM   WS_CTX2      // y head-major overlays ctx2 (dead after k2)

__device__ __forceinline__ unsigned short f2bf(float f) {
    union { float f; unsigned int i; } v; v.f = f;
    unsigned int r = v.i + 0x7fffu + ((v.i >> 16) & 1u);   // RNE
    return (unsigned short)(r >> 16);
}
__device__ __forceinline__ float bflo(unsigned int u) {
    union { unsigned int i; float f; } v; v.i = u << 16; return v.f;
}
__device__ __forceinline__ float bfhi(unsigned int u) {
    union { unsigned int i; float f; } v; v.i = u & 0xffff0000u; return v.f;
}

// ---------------------------------------------------------------------------
// k0: weights -> bf16 in ws; BN (gamma,beta,mean,var) -> (scale,shift)
// ---------------------------------------------------------------------------
__global__ __launch_bounds__(256) void k0_prep(char* __restrict__ ws,
    const float* __restrict__ thW, const float* __restrict__ phW,
    const float* __restrict__ gW,  const float* __restrict__ outW,
    const float* __restrict__ pmW,
    const float* __restrict__ th_g, const float* __restrict__ th_b,
    const float* __restrict__ th_m, const float* __restrict__ th_v,
    const float* __restrict__ ph_g, const float* __restrict__ ph_b,
    const float* __restrict__ ph_m, const float* __restrict__ ph_v,
    const float* __restrict__ g_g,  const float* __restrict__ g_b,
    const float* __restrict__ g_m,  const float* __restrict__ g_v,
    const float* __restrict__ o_g,  const float* __restrict__ o_b,
    const float* __restrict__ o_m,  const float* __restrict__ o_v) {
    int i = blockIdx.x * 256 + threadIdx.x;
    if (i < 524288) {
        int mat = i >> 17, el = i & 131071;
        const float* src = (mat == 0) ? thW : (mat == 1) ? phW : (mat == 2) ? gW : outW;
        ((unsigned short*)ws)[mat * 131072 + el] = f2bf(src[el]);
    } else if (i < 786432) {
        int el = i - 524288;
        ((unsigned short*)(ws + WS_PMW))[el] = f2bf(pmW[el]);
    } else if (i < 786432 + 2560) {
        int j = i - 786432;
        float* bn = (float*)(ws + WS_BN);
        float v;
        if (j < 256)        { int c = j;        v = th_g[c] * rsqrtf(th_v[c] + 1e-5f); }
        else if (j < 512)   { int c = j - 256;  float s = th_g[c] * rsqrtf(th_v[c] + 1e-5f); v = th_b[c] - th_m[c] * s; }
        else if (j < 768)   { int c = j - 512;  v = ph_g[c] * rsqrtf(ph_v[c] + 1e-5f); }
        else if (j < 1024)  { int c = j - 768;  float s = ph_g[c] * rsqrtf(ph_v[c] + 1e-5f); v = ph_b[c] - ph_m[c] * s; }
        else if (j < 1280)  { int c = j - 1024; v = g_g[c] * rsqrtf(g_v[c] + 1e-5f); }
        else if (j < 1536)  { int c = j - 1280; float s = g_g[c] * rsqrtf(g_v[c] + 1e-5f); v = g_b[c] - g_m[c] * s; }
        else if (j < 2048)  { int c = j - 1536; v = o_g[c] * rsqrtf(o_v[c] + 1e-5f); }
        else                { int c = j - 2048; float s = o_g[c] * rsqrtf(o_v[c] + 1e-5f); v = o_b[c] - o_m[c] * s; }
        bn[j] = v;
    }
}

// ---------------------------------------------------------------------------
// k1: position mixing.  ctx2 = context + einsum + pm_b, written q-major bf16.
// ---------------------------------------------------------------------------
__global__ __launch_bounds__(256) void k1_posmix(const float* __restrict__ ctx,
                                                 const float* __restrict__ pm_b,
                                                 char* __restrict__ ws) {
    __shared__ __align__(16) unsigned short stg[2 * 64 * 136];  // pitch 136
    const unsigned short* pmw = (const unsigned short*)(ws + WS_PMW);
    unsigned short* ctx2 = (unsigned short*)(ws + WS_CTX2);
    int t = threadIdx.x, w = t >> 6, l = t & 63, g = l >> 4, li = l & 15;
    int n0 = blockIdx.x * 2;
    int ni = li >> 3, cc = li & 7;  // A row = (n_i, cc)

#pragma unroll 1
    for (int r = 0; r < 4; ++r) {           // 4 channel-slices of 128 (16 heads)
#pragma unroll 1
        for (int hi = 0; hi < 4; ++hi) {
            int h = r * 16 + w * 4 + hi;
            const float* arow = ctx + (size_t)(n0 + ni) * 32768 + (size_t)(h * 8 + cc) * 64;
            bf16x8 a[2];
#pragma unroll
            for (int ks = 0; ks < 2; ++ks) {
                float4 f0 = *(const float4*)(arow + ks * 32 + g * 8);
                float4 f1 = *(const float4*)(arow + ks * 32 + g * 8 + 4);
                bf16x8 av;
                av[0] = (short)f2bf(f0.x); av[1] = (short)f2bf(f0.y);
                av[2] = (short)f2bf(f0.z); av[3] = (short)f2bf(f0.w);
                av[4] = (short)f2bf(f1.x); av[5] = (short)f2bf(f1.y);
                av[6] = (short)f2bf(f1.z); av[7] = (short)f2bf(f1.w);
                a[ks] = av;
            }
#pragma unroll
            for (int nt = 0; nt < 4; ++nt) {
                int q = nt * 16 + li;
                const unsigned short* br = pmw + h * 4096 + q * 64 + g * 8;
                bf16x8 b0 = *(const bf16x8*)br;
                bf16x8 b1 = *(const bf16x8*)(br + 32);
                f32x4 acc = {0.f, 0.f, 0.f, 0.f};
                acc = MFMA16(a[0], b0, acc);
                acc = MFMA16(a[1], b1, acc);
                float pb = pm_b[h * 64 + q];
#pragma unroll
                for (int rr = 0; rr < 4; ++rr) {
                    int row = 4 * g + rr; int n2 = row >> 3, c2 = row & 7;
                    float resid = ctx[(size_t)(n0 + n2) * 32768 + (size_t)(h * 8 + c2) * 64 + q];
                    stg[n2 * 8704 + q * 136 + (h - r * 16) * 8 + c2] = f2bf(acc[rr] + resid + pb);
                }
            }
        }
        __syncthreads();
#pragma unroll 1
        for (int it = 0; it < 8; ++it) {
            int ci = it * 256 + t;
            int n2 = ci >> 10, q = (ci >> 4) & 63, seg = ci & 15;
            uint4 v = *(const uint4*)&stg[n2 * 8704 + q * 136 + seg * 8];
            *(uint4*)(ctx2 + (size_t)(n0 + n2) * 32768 + (size_t)q * 512 + r * 128 + seg * 8) = v;
        }
        __syncthreads();
    }
}

// ---------------------------------------------------------------------------
// k2: theta/phi/g projections.  BN+ReLU, output HEAD-MAJOR [n][h][q][d].
// A: LDS tile [128 rows][64c] XOR-swizzled; B: global bf16 weights.
// Epilogue: LDS transpose (pitch 264) -> coalesced head-major uint2 stores.
// ---------------------------------------------------------------------------
__global__ __launch_bounds__(256) void k2_proj(const float* __restrict__ query,
                                               char* __restrict__ ws) {
    __shared__ __align__(16) unsigned short At[128 * 64];
    int mat = blockIdx.y;
    int n0 = blockIdx.x * 2;
    const unsigned short* W = (const unsigned short*)ws + (size_t)mat * 131072;
    const float* bnm = (const float*)(ws + WS_BN) + mat * 512;
    unsigned short* outp = (unsigned short*)(ws + WS_THQ + (size_t)mat * 33554432u);
    const unsigned short* ctx2 = (const unsigned short*)(ws + WS_CTX2);
    int t = threadIdx.x, w = t >> 6, l = t & 63, g = l >> 4, li = l & 15;

    float sc[4], sh[4];
#pragma unroll
    for (int nti = 0; nti < 4; ++nti) {
        int och = (w * 4 + nti) * 16 + li;
        sc[nti] = bnm[och];
        sh[nti] = bnm[256 + och];
    }

    f32x4 acc[8][4];
#pragma unroll
    for (int mt = 0; mt < 8; ++mt)
#pragma unroll
        for (int nti = 0; nti < 4; ++nti) acc[mt][nti] = (f32x4){0.f, 0.f, 0.f, 0.f};

#pragma unroll 1
    for (int kt = 0; kt < 8; ++kt) {
        // ---- stage A tile (swizzled: logical chunk ch stored at ch^(row&7)) ----
        if (mat == 0) {  // query f32, transpose-on-stage
#pragma unroll 1
            for (int p = 0; p < 8; ++p) {
                int nn = p >> 2, cs = p & 3;
                int cr = cs * 16 + (t >> 4);
                int q4 = t & 15;
                const float* src = query + (size_t)(n0 + nn) * 32768 + (size_t)(kt * 64 + cr) * 64 + q4 * 4;
                float4 f = *(const float4*)src;
#pragma unroll
                for (int kq = 0; kq < 4; ++kq) {
                    int row = nn * 64 + q4 * 4 + kq;
                    int byt = row * 128 + (((cr >> 3) ^ (row & 7)) << 4) + (cr & 7) * 2;
                    float fv = (kq == 0) ? f.x : (kq == 1) ? f.y : (kq == 2) ? f.z : f.w;
                    *(unsigned short*)((char*)At + byt) = f2bf(fv);
                }
            }
        } else {  // ctx2 bf16 q-major: pre-swizzled source, linear LDS dest
#pragma unroll
            for (int it = 0; it < 4; ++it) {
                int ci = it * 256 + t;
                int row = ci >> 3, ch = ci & 7;
                int nn = n0 + (row >> 6), q = row & 63;
                const unsigned short* src = ctx2 + (size_t)nn * 32768 + (size_t)q * 512 + kt * 64 + ((ch ^ (q & 7)) * 8);
                *(uint4*)((char*)At + ci * 16) = *(const uint4*)src;
            }
        }
        __syncthreads();

        bf16x8 b[4][2];
#pragma unroll
        for (int nti = 0; nti < 4; ++nti) {
            const unsigned short* wr = W + (size_t)((w * 4 + nti) * 16 + li) * 512 + kt * 64 + g * 8;
            b[nti][0] = *(const bf16x8*)wr;
            b[nti][1] = *(const bf16x8*)(wr + 32);
        }
#pragma unroll
        for (int mt = 0; mt < 8; ++mt) {
            int row = mt * 16 + li;
            const char* ab = (const char*)At + row * 128;
            bf16x8 a0 = *(const bf16x8*)(ab + (((0 + g) ^ (row & 7)) << 4));
            bf16x8 a1 = *(const bf16x8*)(ab + (((4 + g) ^ (row & 7)) << 4));
#pragma unroll
            for (int nti = 0; nti < 4; ++nti) {
                acc[mt][nti] = MFMA16(a0, b[nti][0], acc[mt][nti]);
                acc[mt][nti] = MFMA16(a1, b[nti][1], acc[mt][nti]);
            }
        }
        __syncthreads();
    }

    // ---- epilogue: BN + ReLU -> head-major via LDS transpose (reuse At) ----
    unsigned short* stg = At;  // [16 rows][pitch 264]
#pragma unroll 1
    for (int mt = 0; mt < 8; ++mt) {
#pragma unroll
        for (int nti = 0; nti < 4; ++nti) {
            int och = (w * 4 + nti) * 16 + li;
#pragma unroll
            for (int rr = 0; rr < 4; ++rr) {
                float v = fmaxf(acc[mt][nti][rr] * sc[nti] + sh[nti], 0.f);
                stg[(4 * g + rr) * 264 + och] = f2bf(v);
            }
        }
        __syncthreads();
        int nn = n0 + (mt >> 2), qb = (mt & 3) * 16;
        unsigned short* ob = outp + (size_t)nn * 16384;
#pragma unroll
        for (int it = 0; it < 4; ++it) {
            int h = it * 16 + w * 4 + g;
            uint2 v = *(const uint2*)&stg[li * 264 + h * 4];
            *(uint2*)(ob + h * 256 + (qb + li) * 4) = v;
        }
        __syncthreads();
    }
}

// ---------------------------------------------------------------------------
// k3: attention.  One wave per (n, head-batch of 8).  Per head:
// S^T = mfma(phi, theta) (K=4 of 32, zero-padded A), column softmax
// (16 in-lane + 2 shfl), VALU PV, coalesced head-major uint2 y store.
// All loads hit the head's contiguous 512B slices.
// ---------------------------------------------------------------------------
__global__ __launch_bounds__(256) void k3_attn(char* __restrict__ ws) {
    int n = blockIdx.x >> 1, half = blockIdx.x & 1;
    const unsigned short* th = (const unsigned short*)(ws + WS_THQ) + (size_t)n * 16384;
    const unsigned short* ph = (const unsigned short*)(ws + WS_THQ + 33554432u) + (size_t)n * 16384;
    const unsigned short* gx = (const unsigned short*)(ws + WS_THQ + 67108864u) + (size_t)n * 16384;
    unsigned short* yout = (unsigned short*)(ws + WS_YHM) + (size_t)n * 16384;
    int t = threadIdx.x, w = t >> 6, l = t & 63, g = l >> 4, li = l & 15;
    const float Cs = 0.72134752044f;  // 0.5 * log2(e)
    f32x4 z4 = {0.f, 0.f, 0.f, 0.f};
    bool zz = (g == 0);

#pragma unroll 1
    for (int hi = 0; hi < 8; ++hi) {
        int h = half * 32 + w * 8 + hi;
        const unsigned short* th_h = th + h * 256;
        const unsigned short* ph_h = ph + h * 256;
        const unsigned short* gx_h = gx + h * 256;
        bf16x8 a[4], b[4];
#pragma unroll
        for (int mt = 0; mt < 4; ++mt) {   // A = phi[k_sp][d] rows, vals at kk=0..3 (g==0)
            uint2 v = *(const uint2*)(ph_h + (mt * 16 + li) * 4);
            short s0 = (short)(v.x & 0xffff), s1 = (short)(v.x >> 16);
            short s2 = (short)(v.y & 0xffff), s3 = (short)(v.y >> 16);
            bf16x8 av;
            av[0] = zz ? s0 : (short)0; av[1] = zz ? s1 : (short)0;
            av[2] = zz ? s2 : (short)0; av[3] = zz ? s3 : (short)0;
            av[4] = 0; av[5] = 0; av[6] = 0; av[7] = 0;
            a[mt] = av;
        }
#pragma unroll
        for (int nt = 0; nt < 4; ++nt) {   // B = theta[q][d] cols
            uint2 v = *(const uint2*)(th_h + (nt * 16 + li) * 4);
            bf16x8 bv;
            bv[0] = (short)(v.x & 0xffff); bv[1] = (short)(v.x >> 16);
            bv[2] = (short)(v.y & 0xffff); bv[3] = (short)(v.y >> 16);
            bv[4] = 0; bv[5] = 0; bv[6] = 0; bv[7] = 0;
            b[nt] = bv;
        }
        f32x4 p[4][4];
#pragma unroll
        for (int mt = 0; mt < 4; ++mt)
#pragma unroll
            for (int nt = 0; nt < 4; ++nt) p[mt][nt] = MFMA16(a[mt], b[nt], z4);

        // column softmax (col q = nt*16+li; rows: 16 in-lane over (mt,rr) + g via shfl)
        float rs[4];
#pragma unroll
        for (int nt = 0; nt < 4; ++nt) {
            float mx = p[0][nt][0];
#pragma unroll
            for (int mt = 0; mt < 4; ++mt)
#pragma unroll
                for (int rr = 0; rr < 4; ++rr) mx = fmaxf(mx, p[mt][nt][rr]);
            mx = fmaxf(mx, __shfl_xor(mx, 16));
            mx = fmaxf(mx, __shfl_xor(mx, 32));
            float nmC = -mx * Cs;
            float sum = 0.f;
#pragma unroll
            for (int mt = 0; mt < 4; ++mt)
#pragma unroll
                for (int rr = 0; rr < 4; ++rr) {
                    float e = exp2f(fmaf(p[mt][nt][rr], Cs, nmC));
                    p[mt][nt][rr] = e;
                    sum += e;
                }
            sum += __shfl_xor(sum, 16);
            sum += __shfl_xor(sum, 32);
            rs[nt] = __builtin_amdgcn_rcpf(sum);
        }
        // PV: y[q][d] = sum_k P^T[k][q] * g[k][d]
        float y[4][4];
#pragma unroll
        for (int nt = 0; nt < 4; ++nt)
#pragma unroll
            for (int d = 0; d < 4; ++d) y[nt][d] = 0.f;
#pragma unroll
        for (int mt = 0; mt < 4; ++mt)
#pragma unroll
            for (int rr = 0; rr < 4; ++rr) {
                int k = mt * 16 + 4 * g + rr;
                uint2 gv = *(const uint2*)(gx_h + k * 4);
                float g0 = bflo(gv.x), g1 = bfhi(gv.x), g2 = bflo(gv.y), g3 = bfhi(gv.y);
#pragma unroll
                for (int nt = 0; nt < 4; ++nt) {
                    float pp = p[mt][nt][rr];
                    y[nt][0] = fmaf(pp, g0, y[nt][0]);
                    y[nt][1] = fmaf(pp, g1, y[nt][1]);
                    y[nt][2] = fmaf(pp, g2, y[nt][2]);
                    y[nt][3] = fmaf(pp, g3, y[nt][3]);
                }
            }
#pragma unroll
        for (int nt = 0; nt < 4; ++nt)
#pragma unroll
            for (int d = 0; d < 4; ++d) {
                float v = y[nt][d];
                v += __shfl_xor(v, 16);
                v += __shfl_xor(v, 32);
                y[nt][d] = v;
            }
        // every lane now has all y[nt][d]; lane l stores q = l (nt = l>>4)
        float rsv = (g & 2) ? ((g & 1) ? rs[3] : rs[2]) : ((g & 1) ? rs[1] : rs[0]);
        float yv0 = (g & 2) ? ((g & 1) ? y[3][0] : y[2][0]) : ((g & 1) ? y[1][0] : y[0][0]);
        float yv1 = (g & 2) ? ((g & 1) ? y[3][1] : y[2][1]) : ((g & 1) ? y[1][1] : y[0][1]);
        float yv2 = (g & 2) ? ((g & 1) ? y[3][2] : y[2][2]) : ((g & 1) ? y[1][2] : y[0][2]);
        float yv3 = (g & 2) ? ((g & 1) ? y[3][3] : y[2][3]) : ((g & 1) ? y[1][3] : y[0][3]);
        uint2 pk;
        pk.x = (unsigned)f2bf(yv0 * rsv) | ((unsigned)f2bf(yv1 * rsv) << 16);
        pk.y = (unsigned)f2bf(yv2 * rsv) | ((unsigned)f2bf(yv3 * rsv) << 16);
        *(uint2*)(yout + h * 256 + l * 4) = pk;   // 512B fully-coalesced per head
    }
}

// ---------------------------------------------------------------------------
// k4: out = query + ReLU(BN(out_W @ y)).  Block = one n.  A = head-major y
// staged linearly in LDS (frags via paired ds_read_b64), B = bf16 out_W.
// ---------------------------------------------------------------------------
__global__ __launch_bounds__(256) void k4_out(const float* __restrict__ query,
                                              char* __restrict__ ws,
                                              float* __restrict__ out) {
    __shared__ __align__(16) unsigned short yA[64 * 256];
    __shared__ float ostg[4][64 * 17];
    int n = blockIdx.x;
    const unsigned short* yQ = (const unsigned short*)(ws + WS_YHM) + (size_t)n * 16384;
    const unsigned short* W = (const unsigned short*)ws + (size_t)3 * 131072;  // out_W bf16
    const float* bn = (const float*)(ws + WS_BN) + 1536;
    int t = threadIdx.x, w = t >> 6, l = t & 63, g = l >> 4, li = l & 15;

    // stage y head-major, linear copy
#pragma unroll 1
    for (int it = 0; it < 8; ++it) {
        int ci = it * 256 + t;
        *(uint4*)((char*)yA + ci * 16) = *(const uint4*)(yQ + ci * 8);
    }
    __syncthreads();

    f32x4 acc[4][8];
#pragma unroll
    for (int mt = 0; mt < 4; ++mt)
#pragma unroll
        for (int nti = 0; nti < 8; ++nti) acc[mt][nti] = (f32x4){0.f, 0.f, 0.f, 0.f};

#pragma unroll 1
    for (int kt = 0; kt < 4; ++kt) {
        bf16x8 a[4][2];
#pragma unroll
        for (int mt = 0; mt < 4; ++mt) {
            int q = mt * 16 + li;
            const char* base = (const char*)yA;
            int c0 = kt * 8 + g, c1 = kt * 8 + 4 + g;   // 8-channel chunks
            union U { uint2 u[2]; bf16x8 v; };
            U u0, u1;
            u0.u[0] = *(const uint2*)(base + c0 * 1024 + q * 8);
            u0.u[1] = *(const uint2*)(base + c0 * 1024 + 512 + q * 8);
            u1.u[0] = *(const uint2*)(base + c1 * 1024 + q * 8);
            u1.u[1] = *(const uint2*)(base + c1 * 1024 + 512 + q * 8);
            a[mt][0] = u0.v;
            a[mt][1] = u1.v;
        }
#pragma unroll
        for (int nti = 0; nti < 8; ++nti) {
            int och = w * 128 + nti * 16 + li;
            const unsigned short* wr = W + (size_t)och * 256 + kt * 64 + g * 8;
            bf16x8 b0 = *(const bf16x8*)wr;
            bf16x8 b1 = *(const bf16x8*)(wr + 32);
#pragma unroll
            for (int mt = 0; mt < 4; ++mt) {
                acc[mt][nti] = MFMA16(a[mt][0], b0, acc[mt][nti]);
                acc[mt][nti] = MFMA16(a[mt][1], b1, acc[mt][nti]);
            }
        }
    }

    // epilogue: per 16-och round, LDS transpose -> coalesced ch-major stores
#pragma unroll 1
    for (int nti = 0; nti < 8; ++nti) {
        int och0 = w * 128 + nti * 16;
        float sc = bn[och0 + li], sb = bn[512 + och0 + li];
#pragma unroll
        for (int mt = 0; mt < 4; ++mt)
#pragma unroll
            for (int rr = 0; rr < 4; ++rr) {
                int q = mt * 16 + 4 * g + rr;
                ostg[w][q * 17 + li] = fmaxf(acc[mt][nti][rr] * sc + sb, 0.f);
            }
        __syncthreads();
#pragma unroll 1
        for (int ii = 0; ii < 16; ++ii) {
            int ocl = (ii & 3) * 4 + g;
            int q = (ii >> 2) * 16 + li;
            float v = ostg[w][q * 17 + ocl];
            size_t idx = (size_t)n * 32768 + (size_t)(och0 + ocl) * 64 + q;
            out[idx] = query[idx] + v;
        }
        __syncthreads();
    }
}

// ---------------------------------------------------------------------------
extern "C" void kernel_launch(void* const* d_in, const int* in_sizes, int n_in,
                              void* d_out, int out_size, void* d_ws, size_t ws_size,
                              hipStream_t stream) {
    (void)in_sizes; (void)n_in; (void)out_size; (void)ws_size;
    const float* query   = (const float*)d_in[0];
    const float* context = (const float*)d_in[1];
    const float* pm_W    = (const float*)d_in[2];
    const float* pm_b    = (const float*)d_in[3];
    const float* g_W     = (const float*)d_in[4];
    const float* g_g     = (const float*)d_in[5];
    const float* g_b     = (const float*)d_in[6];
    const float* g_m     = (const float*)d_in[7];
    const float* g_v     = (const float*)d_in[8];
    const float* th_W    = (const float*)d_in[9];
    const float* th_g    = (const float*)d_in[10];
    const float* th_b    = (const float*)d_in[11];
    const float* th_m    = (const float*)d_in[12];
    const float* th_v    = (const float*)d_in[13];
    const float* ph_W    = (const float*)d_in[14];
    const float* ph_g    = (const float*)d_in[15];
    const float* ph_b    = (const float*)d_in[16];
    const float* ph_m    = (const float*)d_in[17];
    const float* ph_v    = (const float*)d_in[18];
    const float* o_W     = (const float*)d_in[19];
    const float* o_g     = (const float*)d_in[20];
    const float* o_b     = (const float*)d_in[21];
    const float* o_m     = (const float*)d_in[22];
    const float* o_v     = (const float*)d_in[23];
    char* ws = (char*)d_ws;

    k0_prep<<<3082, 256, 0, stream>>>(ws, th_W, ph_W, g_W, o_W, pm_W,
                                      th_g, th_b, th_m, th_v,
                                      ph_g, ph_b, ph_m, ph_v,
                                      g_g, g_b, g_m, g_v,
                                      o_g, o_b, o_m, o_v);
    k1_posmix<<<512, 256, 0, stream>>>(context, pm_b, ws);
    k2_proj<<<dim3(512, 3, 1), 256, 0, stream>>>(query, ws);
    k3_attn<<<2048, 256, 0, stream>>>(ws);
    k4_out<<<1024, 256, 0, stream>>>(query, ws, (float*)d_out);
}

// Round 3
// 622.443 us; speedup vs baseline: 1.4006x; 1.4006x over previous
//
#include <hip/hip_runtime.h>
#include <stdint.h>

// ---------------------------------------------------------------------------
// LawinAttn fused pipeline for MI355X (gfx950).
// k0 prep (bf16 weights + BN fold), k1 posmix (-> q-major ctx2),
// k2 theta/phi/g projections (MFMA GEMM, HEAD-MAJOR output [n][h][q][d]),
// k3 per-head attention (contiguous per-head slices), k4 out proj.
// NOTE: all accumulator arrays are indexed ONLY with compile-time-constant
// indices (fully unrolled loops) -- runtime indexing spills to scratch (r2).
// ---------------------------------------------------------------------------

typedef short bf16x8 __attribute__((ext_vector_type(8)));
typedef float f32x4 __attribute__((ext_vector_type(4)));

#define MFMA16(a, b, c) __builtin_amdgcn_mfma_f32_16x16x32_bf16((a), (b), (c), 0, 0, 0)

// ws byte offsets
#define WS_W     0u           // 4 x 131072 bf16 weights: [theta|phi|g|out]
#define WS_BN    1048576u     // 2560 f32
#define WS_PMW   1058816u     // 262144 bf16 (pm_W)
#define WS_CTX2  2097152u     // 1024*64*512 bf16 q-major ctx2 (later reused as y)
#define WS_THQ   69206016u    // 3 x 1024*64*256 bf16 HEAD-MAJOR theta/phi/g
#define WS_YHM   WS_CTX2      // y head-major overlays ctx2 (dead after k2)

__device__ __forceinline__ unsigned short f2bf(float f) {
    union { float f; unsigned int i; } v; v.f = f;
    unsigned int r = v.i + 0x7fffu + ((v.i >> 16) & 1u);   // RNE
    return (unsigned short)(r >> 16);
}
__device__ __forceinline__ float bflo(unsigned int u) {
    union { unsigned int i; float f; } v; v.i = u << 16; return v.f;
}
__device__ __forceinline__ float bfhi(unsigned int u) {
    union { unsigned int i; float f; } v; v.i = u & 0xffff0000u; return v.f;
}

// ---------------------------------------------------------------------------
// k0: weights -> bf16 in ws; BN (gamma,beta,mean,var) -> (scale,shift)
// ---------------------------------------------------------------------------
__global__ __launch_bounds__(256) void k0_prep(char* __restrict__ ws,
    const float* __restrict__ thW, const float* __restrict__ phW,
    const float* __restrict__ gW,  const float* __restrict__ outW,
    const float* __restrict__ pmW,
    const float* __restrict__ th_g, const float* __restrict__ th_b,
    const float* __restrict__ th_m, const float* __restrict__ th_v,
    const float* __restrict__ ph_g, const float* __restrict__ ph_b,
    const float* __restrict__ ph_m, const float* __restrict__ ph_v,
    const float* __restrict__ g_g,  const float* __restrict__ g_b,
    const float* __restrict__ g_m,  const float* __restrict__ g_v,
    const float* __restrict__ o_g,  const float* __restrict__ o_b,
    const float* __restrict__ o_m,  const float* __restrict__ o_v) {
    int i = blockIdx.x * 256 + threadIdx.x;
    if (i < 524288) {
        int mat = i >> 17, el = i & 131071;
        const float* src = (mat == 0) ? thW : (mat == 1) ? phW : (mat == 2) ? gW : outW;
        ((unsigned short*)ws)[mat * 131072 + el] = f2bf(src[el]);
    } else if (i < 786432) {
        int el = i - 524288;
        ((unsigned short*)(ws + WS_PMW))[el] = f2bf(pmW[el]);
    } else if (i < 786432 + 2560) {
        int j = i - 786432;
        float* bn = (float*)(ws + WS_BN);
        float v;
        if (j < 256)        { int c = j;        v = th_g[c] * rsqrtf(th_v[c] + 1e-5f); }
        else if (j < 512)   { int c = j - 256;  float s = th_g[c] * rsqrtf(th_v[c] + 1e-5f); v = th_b[c] - th_m[c] * s; }
        else if (j < 768)   { int c = j - 512;  v = ph_g[c] * rsqrtf(ph_v[c] + 1e-5f); }
        else if (j < 1024)  { int c = j - 768;  float s = ph_g[c] * rsqrtf(ph_v[c] + 1e-5f); v = ph_b[c] - ph_m[c] * s; }
        else if (j < 1280)  { int c = j - 1024; v = g_g[c] * rsqrtf(g_v[c] + 1e-5f); }
        else if (j < 1536)  { int c = j - 1280; float s = g_g[c] * rsqrtf(g_v[c] + 1e-5f); v = g_b[c] - g_m[c] * s; }
        else if (j < 2048)  { int c = j - 1536; v = o_g[c] * rsqrtf(o_v[c] + 1e-5f); }
        else                { int c = j - 2048; float s = o_g[c] * rsqrtf(o_v[c] + 1e-5f); v = o_b[c] - o_m[c] * s; }
        bn[j] = v;
    }
}

// ---------------------------------------------------------------------------
// k1: position mixing.  ctx2 = context + einsum + pm_b, written q-major bf16.
// ---------------------------------------------------------------------------
__global__ __launch_bounds__(256) void k1_posmix(const float* __restrict__ ctx,
                                                 const float* __restrict__ pm_b,
                                                 char* __restrict__ ws) {
    __shared__ __align__(16) unsigned short stg[2 * 64 * 136];  // pitch 136
    const unsigned short* pmw = (const unsigned short*)(ws + WS_PMW);
    unsigned short* ctx2 = (unsigned short*)(ws + WS_CTX2);
    int t = threadIdx.x, w = t >> 6, l = t & 63, g = l >> 4, li = l & 15;
    int n0 = blockIdx.x * 2;
    int ni = li >> 3, cc = li & 7;  // A row = (n_i, cc)

#pragma unroll 1
    for (int r = 0; r < 4; ++r) {           // 4 channel-slices of 128 (16 heads)
#pragma unroll 1
        for (int hi = 0; hi < 4; ++hi) {
            int h = r * 16 + w * 4 + hi;
            const float* arow = ctx + (size_t)(n0 + ni) * 32768 + (size_t)(h * 8 + cc) * 64;
            bf16x8 a[2];
#pragma unroll
            for (int ks = 0; ks < 2; ++ks) {
                float4 f0 = *(const float4*)(arow + ks * 32 + g * 8);
                float4 f1 = *(const float4*)(arow + ks * 32 + g * 8 + 4);
                bf16x8 av;
                av[0] = (short)f2bf(f0.x); av[1] = (short)f2bf(f0.y);
                av[2] = (short)f2bf(f0.z); av[3] = (short)f2bf(f0.w);
                av[4] = (short)f2bf(f1.x); av[5] = (short)f2bf(f1.y);
                av[6] = (short)f2bf(f1.z); av[7] = (short)f2bf(f1.w);
                a[ks] = av;
            }
#pragma unroll
            for (int nt = 0; nt < 4; ++nt) {
                int q = nt * 16 + li;
                const unsigned short* br = pmw + h * 4096 + q * 64 + g * 8;
                bf16x8 b0 = *(const bf16x8*)br;
                bf16x8 b1 = *(const bf16x8*)(br + 32);
                f32x4 acc = {0.f, 0.f, 0.f, 0.f};
                acc = MFMA16(a[0], b0, acc);
                acc = MFMA16(a[1], b1, acc);
                float pb = pm_b[h * 64 + q];
#pragma unroll
                for (int rr = 0; rr < 4; ++rr) {
                    int row = 4 * g + rr; int n2 = row >> 3, c2 = row & 7;
                    float resid = ctx[(size_t)(n0 + n2) * 32768 + (size_t)(h * 8 + c2) * 64 + q];
                    stg[n2 * 8704 + q * 136 + (h - r * 16) * 8 + c2] = f2bf(acc[rr] + resid + pb);
                }
            }
        }
        __syncthreads();
#pragma unroll 1
        for (int it = 0; it < 8; ++it) {
            int ci = it * 256 + t;
            int n2 = ci >> 10, q = (ci >> 4) & 63, seg = ci & 15;
            uint4 v = *(const uint4*)&stg[n2 * 8704 + q * 136 + seg * 8];
            *(uint4*)(ctx2 + (size_t)(n0 + n2) * 32768 + (size_t)q * 512 + r * 128 + seg * 8) = v;
        }
        __syncthreads();
    }
}

// ---------------------------------------------------------------------------
// k2: theta/phi/g projections.  BN+ReLU, output HEAD-MAJOR [n][h][q][d].
// A: LDS tile [128 rows][64c] XOR-swizzled; B: global bf16 weights.
// Epilogue: LDS transpose (pitch 260) -> coalesced head-major uint2 stores.
// Epilogue loops FULLY UNROLLED so acc[][] indices stay compile-time const.
// ---------------------------------------------------------------------------
__global__ __launch_bounds__(256) void k2_proj(const float* __restrict__ query,
                                               char* __restrict__ ws) {
    __shared__ __align__(16) unsigned short At[128 * 64];
    int mat = blockIdx.y;
    int n0 = blockIdx.x * 2;
    const unsigned short* W = (const unsigned short*)ws + (size_t)mat * 131072;
    const float* bnm = (const float*)(ws + WS_BN) + mat * 512;
    unsigned short* outp = (unsigned short*)(ws + WS_THQ + (size_t)mat * 33554432u);
    const unsigned short* ctx2 = (const unsigned short*)(ws + WS_CTX2);
    int t = threadIdx.x, w = t >> 6, l = t & 63, g = l >> 4, li = l & 15;

    float sc[4], sh[4];
#pragma unroll
    for (int nti = 0; nti < 4; ++nti) {
        int och = (w * 4 + nti) * 16 + li;
        sc[nti] = bnm[och];
        sh[nti] = bnm[256 + och];
    }

    f32x4 acc[8][4];
#pragma unroll
    for (int mt = 0; mt < 8; ++mt)
#pragma unroll
        for (int nti = 0; nti < 4; ++nti) acc[mt][nti] = (f32x4){0.f, 0.f, 0.f, 0.f};

#pragma unroll 1
    for (int kt = 0; kt < 8; ++kt) {
        // ---- stage A tile (swizzled: logical chunk ch stored at ch^(row&7)) ----
        if (mat == 0) {  // query f32, transpose-on-stage
#pragma unroll 1
            for (int p = 0; p < 8; ++p) {
                int nn = p >> 2, cs = p & 3;
                int cr = cs * 16 + (t >> 4);
                int q4 = t & 15;
                const float* src = query + (size_t)(n0 + nn) * 32768 + (size_t)(kt * 64 + cr) * 64 + q4 * 4;
                float4 f = *(const float4*)src;
#pragma unroll
                for (int kq = 0; kq < 4; ++kq) {
                    int row = nn * 64 + q4 * 4 + kq;
                    int byt = row * 128 + (((cr >> 3) ^ (row & 7)) << 4) + (cr & 7) * 2;
                    float fv = (kq == 0) ? f.x : (kq == 1) ? f.y : (kq == 2) ? f.z : f.w;
                    *(unsigned short*)((char*)At + byt) = f2bf(fv);
                }
            }
        } else {  // ctx2 bf16 q-major: pre-swizzled source, linear LDS dest
#pragma unroll
            for (int it = 0; it < 4; ++it) {
                int ci = it * 256 + t;
                int row = ci >> 3, ch = ci & 7;
                int nn = n0 + (row >> 6), q = row & 63;
                const unsigned short* src = ctx2 + (size_t)nn * 32768 + (size_t)q * 512 + kt * 64 + ((ch ^ (q & 7)) * 8);
                *(uint4*)((char*)At + ci * 16) = *(const uint4*)src;
            }
        }
        __syncthreads();

        bf16x8 b[4][2];
#pragma unroll
        for (int nti = 0; nti < 4; ++nti) {
            const unsigned short* wr = W + (size_t)((w * 4 + nti) * 16 + li) * 512 + kt * 64 + g * 8;
            b[nti][0] = *(const bf16x8*)wr;
            b[nti][1] = *(const bf16x8*)(wr + 32);
        }
#pragma unroll
        for (int mt = 0; mt < 8; ++mt) {
            int row = mt * 16 + li;
            const char* ab = (const char*)At + row * 128;
            bf16x8 a0 = *(const bf16x8*)(ab + (((0 + g) ^ (row & 7)) << 4));
            bf16x8 a1 = *(const bf16x8*)(ab + (((4 + g) ^ (row & 7)) << 4));
#pragma unroll
            for (int nti = 0; nti < 4; ++nti) {
                acc[mt][nti] = MFMA16(a0, b[nti][0], acc[mt][nti]);
                acc[mt][nti] = MFMA16(a1, b[nti][1], acc[mt][nti]);
            }
        }
        __syncthreads();
    }

    // ---- epilogue: BN + ReLU -> head-major via LDS transpose (reuse At) ----
    // FULLY UNROLLED (static acc indices).  Pitch 260 shorts: row-start bank
    // = 2*row mod 32 -> the 4 g-groups hit disjoint bank octets (2-way max).
    unsigned short* stg = At;  // [16 rows][pitch 260]
#pragma unroll
    for (int mt = 0; mt < 8; ++mt) {
#pragma unroll
        for (int nti = 0; nti < 4; ++nti) {
            int och = (w * 4 + nti) * 16 + li;
#pragma unroll
            for (int rr = 0; rr < 4; ++rr) {
                float v = fmaxf(acc[mt][nti][rr] * sc[nti] + sh[nti], 0.f);
                stg[(4 * g + rr) * 260 + och] = f2bf(v);
            }
        }
        __syncthreads();
        int nn = n0 + (mt >> 2), qb = (mt & 3) * 16;
        unsigned short* ob = outp + (size_t)nn * 16384;
#pragma unroll
        for (int it = 0; it < 4; ++it) {
            int h = it * 16 + w * 4 + g;
            unsigned short s0 = stg[li * 260 + h * 4 + 0];
            unsigned short s1 = stg[li * 260 + h * 4 + 1];
            unsigned short s2 = stg[li * 260 + h * 4 + 2];
            unsigned short s3 = stg[li * 260 + h * 4 + 3];
            uint2 v;
            v.x = (unsigned)s0 | ((unsigned)s1 << 16);
            v.y = (unsigned)s2 | ((unsigned)s3 << 16);
            *(uint2*)(ob + h * 256 + (qb + li) * 4) = v;
        }
        __syncthreads();
    }
}

// ---------------------------------------------------------------------------
// k3: attention.  One wave per (n, head-batch of 8).  Per head:
// S^T = mfma(phi, theta) (K=4 of 32, zero-padded A), column softmax
// (16 in-lane + 2 shfl), VALU PV, coalesced head-major uint2 y store.
// ---------------------------------------------------------------------------
__global__ __launch_bounds__(256) void k3_attn(char* __restrict__ ws) {
    int n = blockIdx.x >> 1, half = blockIdx.x & 1;
    const unsigned short* th = (const unsigned short*)(ws + WS_THQ) + (size_t)n * 16384;
    const unsigned short* ph = (const unsigned short*)(ws + WS_THQ + 33554432u) + (size_t)n * 16384;
    const unsigned short* gx = (const unsigned short*)(ws + WS_THQ + 67108864u) + (size_t)n * 16384;
    unsigned short* yout = (unsigned short*)(ws + WS_YHM) + (size_t)n * 16384;
    int t = threadIdx.x, w = t >> 6, l = t & 63, g = l >> 4, li = l & 15;
    const float Cs = 0.72134752044f;  // 0.5 * log2(e)
    f32x4 z4 = {0.f, 0.f, 0.f, 0.f};
    bool zz = (g == 0);

#pragma unroll 1
    for (int hi = 0; hi < 8; ++hi) {
        int h = half * 32 + w * 8 + hi;
        const unsigned short* th_h = th + h * 256;
        const unsigned short* ph_h = ph + h * 256;
        const unsigned short* gx_h = gx + h * 256;
        bf16x8 a[4], b[4];
#pragma unroll
        for (int mt = 0; mt < 4; ++mt) {   // A = phi[k_sp][d] rows, vals at kk=0..3 (g==0)
            uint2 v = *(const uint2*)(ph_h + (mt * 16 + li) * 4);
            short s0 = (short)(v.x & 0xffff), s1 = (short)(v.x >> 16);
            short s2 = (short)(v.y & 0xffff), s3 = (short)(v.y >> 16);
            bf16x8 av;
            av[0] = zz ? s0 : (short)0; av[1] = zz ? s1 : (short)0;
            av[2] = zz ? s2 : (short)0; av[3] = zz ? s3 : (short)0;
            av[4] = 0; av[5] = 0; av[6] = 0; av[7] = 0;
            a[mt] = av;
        }
#pragma unroll
        for (int nt = 0; nt < 4; ++nt) {   // B = theta[q][d] cols
            uint2 v = *(const uint2*)(th_h + (nt * 16 + li) * 4);
            bf16x8 bv;
            bv[0] = (short)(v.x & 0xffff); bv[1] = (short)(v.x >> 16);
            bv[2] = (short)(v.y & 0xffff); bv[3] = (short)(v.y >> 16);
            bv[4] = 0; bv[5] = 0; bv[6] = 0; bv[7] = 0;
            b[nt] = bv;
        }
        f32x4 p[4][4];
#pragma unroll
        for (int mt = 0; mt < 4; ++mt)
#pragma unroll
            for (int nt = 0; nt < 4; ++nt) p[mt][nt] = MFMA16(a[mt], b[nt], z4);

        // column softmax (col q = nt*16+li; rows: 16 in-lane over (mt,rr) + g via shfl)
        float rs[4];
#pragma unroll
        for (int nt = 0; nt < 4; ++nt) {
            float mx = p[0][nt][0];
#pragma unroll
            for (int mt = 0; mt < 4; ++mt)
#pragma unroll
                for (int rr = 0; rr < 4; ++rr) mx = fmaxf(mx, p[mt][nt][rr]);
            mx = fmaxf(mx, __shfl_xor(mx, 16));
            mx = fmaxf(mx, __shfl_xor(mx, 32));
            float nmC = -mx * Cs;
            float sum = 0.f;
#pragma unroll
            for (int mt = 0; mt < 4; ++mt)
#pragma unroll
                for (int rr = 0; rr < 4; ++rr) {
                    float e = exp2f(fmaf(p[mt][nt][rr], Cs, nmC));
                    p[mt][nt][rr] = e;
                    sum += e;
                }
            sum += __shfl_xor(sum, 16);
            sum += __shfl_xor(sum, 32);
            rs[nt] = __builtin_amdgcn_rcpf(sum);
        }
        // PV: y[q][d] = sum_k P^T[k][q] * g[k][d]
        float y[4][4];
#pragma unroll
        for (int nt = 0; nt < 4; ++nt)
#pragma unroll
            for (int d = 0; d < 4; ++d) y[nt][d] = 0.f;
#pragma unroll
        for (int mt = 0; mt < 4; ++mt)
#pragma unroll
            for (int rr = 0; rr < 4; ++rr) {
                int k = mt * 16 + 4 * g + rr;
                uint2 gv = *(const uint2*)(gx_h + k * 4);
                float g0 = bflo(gv.x), g1 = bfhi(gv.x), g2 = bflo(gv.y), g3 = bfhi(gv.y);
#pragma unroll
                for (int nt = 0; nt < 4; ++nt) {
                    float pp = p[mt][nt][rr];
                    y[nt][0] = fmaf(pp, g0, y[nt][0]);
                    y[nt][1] = fmaf(pp, g1, y[nt][1]);
                    y[nt][2] = fmaf(pp, g2, y[nt][2]);
                    y[nt][3] = fmaf(pp, g3, y[nt][3]);
                }
            }
#pragma unroll
        for (int nt = 0; nt < 4; ++nt)
#pragma unroll
            for (int d = 0; d < 4; ++d) {
                float v = y[nt][d];
                v += __shfl_xor(v, 16);
                v += __shfl_xor(v, 32);
                y[nt][d] = v;
            }
        // every lane now has all y[nt][d]; lane l stores q = l (nt = g)
        float rsv = (g & 2) ? ((g & 1) ? rs[3] : rs[2]) : ((g & 1) ? rs[1] : rs[0]);
        float yv0 = (g & 2) ? ((g & 1) ? y[3][0] : y[2][0]) : ((g & 1) ? y[1][0] : y[0][0]);
        float yv1 = (g & 2) ? ((g & 1) ? y[3][1] : y[2][1]) : ((g & 1) ? y[1][1] : y[0][1]);
        float yv2 = (g & 2) ? ((g & 1) ? y[3][2] : y[2][2]) : ((g & 1) ? y[1][2] : y[0][2]);
        float yv3 = (g & 2) ? ((g & 1) ? y[3][3] : y[2][3]) : ((g & 1) ? y[1][3] : y[0][3]);
        uint2 pk;
        pk.x = (unsigned)f2bf(yv0 * rsv) | ((unsigned)f2bf(yv1 * rsv) << 16);
        pk.y = (unsigned)f2bf(yv2 * rsv) | ((unsigned)f2bf(yv3 * rsv) << 16);
        *(uint2*)(yout + h * 256 + l * 4) = pk;   // 512B fully-coalesced per head
    }
}

// ---------------------------------------------------------------------------
// k4: out = query + ReLU(BN(out_W @ y)).  Block = one n.  A = head-major y
// staged linearly in LDS (frags via paired ds_read_b64), B = bf16 out_W.
// Epilogue FULLY UNROLLED (static acc indices).
// ---------------------------------------------------------------------------
__global__ __launch_bounds__(256) void k4_out(const float* __restrict__ query,
                                              char* __restrict__ ws,
                                              float* __restrict__ out) {
    __shared__ __align__(16) unsigned short yA[64 * 256];
    __shared__ float ostg[4][64 * 17];
    int n = blockIdx.x;
    const unsigned short* yQ = (const unsigned short*)(ws + WS_YHM) + (size_t)n * 16384;
    const unsigned short* W = (const unsigned short*)ws + (size_t)3 * 131072;  // out_W bf16
    const float* bn = (const float*)(ws + WS_BN) + 1536;
    int t = threadIdx.x, w = t >> 6, l = t & 63, g = l >> 4, li = l & 15;

    // stage y head-major, linear copy
#pragma unroll 1
    for (int it = 0; it < 8; ++it) {
        int ci = it * 256 + t;
        *(uint4*)((char*)yA + ci * 16) = *(const uint4*)(yQ + ci * 8);
    }
    __syncthreads();

    f32x4 acc[4][8];
#pragma unroll
    for (int mt = 0; mt < 4; ++mt)
#pragma unroll
        for (int nti = 0; nti < 8; ++nti) acc[mt][nti] = (f32x4){0.f, 0.f, 0.f, 0.f};

#pragma unroll 1
    for (int kt = 0; kt < 4; ++kt) {
        bf16x8 a[4][2];
#pragma unroll
        for (int mt = 0; mt < 4; ++mt) {
            int q = mt * 16 + li;
            const char* base = (const char*)yA;
            int c0 = kt * 8 + g, c1 = kt * 8 + 4 + g;   // 8-channel chunks
            union U { uint2 u[2]; bf16x8 v; };
            U u0, u1;
            u0.u[0] = *(const uint2*)(base + c0 * 1024 + q * 8);
            u0.u[1] = *(const uint2*)(base + c0 * 1024 + 512 + q * 8);
            u1.u[0] = *(const uint2*)(base + c1 * 1024 + q * 8);
            u1.u[1] = *(const uint2*)(base + c1 * 1024 + 512 + q * 8);
            a[mt][0] = u0.v;
            a[mt][1] = u1.v;
        }
#pragma unroll
        for (int nti = 0; nti < 8; ++nti) {
            int och = w * 128 + nti * 16 + li;
            const unsigned short* wr = W + (size_t)och * 256 + kt * 64 + g * 8;
            bf16x8 b0 = *(const bf16x8*)wr;
            bf16x8 b1 = *(const bf16x8*)(wr + 32);
#pragma unroll
            for (int mt = 0; mt < 4; ++mt) {
                acc[mt][nti] = MFMA16(a[mt][0], b0, acc[mt][nti]);
                acc[mt][nti] = MFMA16(a[mt][1], b1, acc[mt][nti]);
            }
        }
    }

    // epilogue: per 16-och round, LDS transpose -> coalesced ch-major stores
#pragma unroll
    for (int nti = 0; nti < 8; ++nti) {
        int och0 = w * 128 + nti * 16;
        float sc = bn[och0 + li], sb = bn[512 + och0 + li];
#pragma unroll
        for (int mt = 0; mt < 4; ++mt)
#pragma unroll
            for (int rr = 0; rr < 4; ++rr) {
                int q = mt * 16 + 4 * g + rr;
                ostg[w][q * 17 + li] = fmaxf(acc[mt][nti][rr] * sc + sb, 0.f);
            }
        __syncthreads();
#pragma unroll 1
        for (int ii = 0; ii < 16; ++ii) {
            int ocl = (ii & 3) * 4 + g;
            int q = (ii >> 2) * 16 + li;
            float v = ostg[w][q * 17 + ocl];
            size_t idx = (size_t)n * 32768 + (size_t)(och0 + ocl) * 64 + q;
            out[idx] = query[idx] + v;
        }
        __syncthreads();
    }
}

// ---------------------------------------------------------------------------
extern "C" void kernel_launch(void* const* d_in, const int* in_sizes, int n_in,
                              void* d_out, int out_size, void* d_ws, size_t ws_size,
                              hipStream_t stream) {
    (void)in_sizes; (void)n_in; (void)out_size; (void)ws_size;
    const float* query   = (const float*)d_in[0];
    const float* context = (const float*)d_in[1];
    const float* pm_W    = (const float*)d_in[2];
    const float* pm_b    = (const float*)d_in[3];
    const float* g_W     = (const float*)d_in[4];
    const float* g_g     = (const float*)d_in[5];
    const float* g_b     = (const float*)d_in[6];
    const float* g_m     = (const float*)d_in[7];
    const float* g_v     = (const float*)d_in[8];
    const float* th_W    = (const float*)d_in[9];
    const float* th_g    = (const float*)d_in[10];
    const float* th_b    = (const float*)d_in[11];
    const float* th_m    = (const float*)d_in[12];
    const float* th_v    = (const float*)d_in[13];
    const float* ph_W    = (const float*)d_in[14];
    const float* ph_g    = (const float*)d_in[15];
    const float* ph_b    = (const float*)d_in[16];
    const float* ph_m    = (const float*)d_in[17];
    const float* ph_v    = (const float*)d_in[18];
    const float* o_W     = (const float*)d_in[19];
    const float* o_g     = (const float*)d_in[20];
    const float* o_b     = (const float*)d_in[21];
    const float* o_m     = (const float*)d_in[22];
    const float* o_v     = (const float*)d_in[23];
    char* ws = (char*)d_ws;

    k0_prep<<<3082, 256, 0, stream>>>(ws, th_W, ph_W, g_W, o_W, pm_W,
                                      th_g, th_b, th_m, th_v,
                                      ph_g, ph_b, ph_m, ph_v,
                                      g_g, g_b, g_m, g_v,
                                      o_g, o_b, o_m, o_v);
    k1_posmix<<<512, 256, 0, stream>>>(context, pm_b, ws);
    k2_proj<<<dim3(512, 3, 1), 256, 0, stream>>>(query, ws);
    k3_attn<<<2048, 256, 0, stream>>>(ws);
    k4_out<<<1024, 256, 0, stream>>>(query, ws, (float*)d_out);
}